// Round 1
// baseline (254.962 us; speedup 1.0000x reference)
//
#include <hip/hip_runtime.h>
#include <cstdint>
#include <cstddef>

// Problem constants (from reference)
#define NUM_KV   8
#define GQA      2
#define HD       128
#define QSTRIDE  (NUM_KV * GQA * HD)  // 2048
#define KSTRIDE  (NUM_KV * HD)        // 1024
// (1/sqrt(128)) * log2(e) folded into Q's bf16 conversion; softmax done base-2.
#define SCALE_LOG2E 0.12751741032075463f

typedef float    f32x4  __attribute__((ext_vector_type(4)));
typedef unsigned u32x4  __attribute__((ext_vector_type(4)));
typedef __bf16   bf16x8 __attribute__((ext_vector_type(8)));

union U8 {
    unsigned short u[8];
    u32x4 q;
    bf16x8 v;
};

__device__ inline unsigned short f2b(float f) {
    union { float f; unsigned u; } x;
    x.f = f;
    unsigned r = x.u + 0x7fffu + ((x.u >> 16) & 1u);  // RNE bf16 (inputs are finite)
    return (unsigned short)(r >> 16);
}

// LDS row strides (bf16 elements), chosen 16B-aligned & conflict-free for b128 reads
#define KS_STRIDE 136   // 128 + 8 pad
#define VT_STRIDE 40    // 32 keys + 8 pad (transposed V: [d][key])
#define PS_STRIDE 40    // 32 keys + 8 pad

__global__ __launch_bounds__(256, 2)
void attn_kernel(const float* __restrict__ qg, const float* __restrict__ kg,
                 const float* __restrict__ vg, const int* __restrict__ pos,
                 float* __restrict__ out, int T)
{
    __shared__ __align__(16) unsigned short Ks[32 * KS_STRIDE];      // K tile, row-major [key][d]
    __shared__ __align__(16) unsigned short Vt[HD * VT_STRIDE];      // V tile, transposed [d][key]
    __shared__ __align__(16) unsigned short Ps[4 * 16 * PS_STRIDE];  // per-wave P buffer

    const int tid  = threadIdx.x;
    const int w    = tid >> 6;      // wave 0..3
    const int lane = tid & 63;
    const int li   = lane & 15;     // index within 16-group
    const int quad = lane >> 4;     // 0..3

    const int qtile = blockIdx.x;
    const int kvh   = blockIdx.y;
    const int qbase = qtile * 32;
    if (qbase >= T) return;

    const int g    = w >> 1;               // q-head within GQA group
    const int hq   = kvh * GQA + g;        // global q-head
    const int row0 = qbase + (w & 1) * 16; // this wave's first q row

    const int kend = min(qbase + 32, T);
    const int k_lo = qbase - pos[qbase];   // segment start of first row (uniform)

    // Per-lane row info: rows row0 + quad*4 + r  (C-frag row mapping)
    int rowg[4], rstart[4];
#pragma unroll
    for (int r = 0; r < 4; ++r) {
        int rg = row0 + quad * 4 + r;
        int rc = min(rg, T - 1);
        rowg[r]   = rg;
        rstart[r] = rc - pos[rc];
    }

    // ---- Load Q A-frags (bf16, scale*log2e folded in) ----
    // A[m=lane&15][k = c*32 + quad*8 + j]
    bf16x8 qf[4];
    {
        const int qr = min(row0 + li, T - 1);
        const float* qp = qg + (size_t)qr * QSTRIDE + hq * HD + quad * 8;
#pragma unroll
        for (int c = 0; c < 4; ++c) {
            f32x4 f0 = ((const f32x4*)(qp + c * 32))[0];
            f32x4 f1 = ((const f32x4*)(qp + c * 32))[1];
            U8 u;
#pragma unroll
            for (int j = 0; j < 4; ++j) {
                u.u[j]     = f2b(f0[j] * SCALE_LOG2E);
                u.u[4 + j] = f2b(f1[j] * SCALE_LOG2E);
            }
            qf[c] = u.v;
        }
    }

    f32x4 acc[8];
#pragma unroll
    for (int nt = 0; nt < 8; ++nt) acc[nt] = (f32x4){0.f, 0.f, 0.f, 0.f};
    float m_i[4], l_i[4];
#pragma unroll
    for (int r = 0; r < 4; ++r) { m_i[r] = -1e30f; l_i[r] = 0.f; }

    // staging thread mappings
    const int kr  = tid >> 3;   // 0..31  K row
    const int dq  = tid & 7;    // 0..7   16-d chunk (K)
    const int dq8 = tid >> 4;   // 0..15  8-d chunk (V)
    const int krp = tid & 15;   // 0..15  key pair (V)

    for (int kb = k_lo; kb < kend; kb += 32) {
        __syncthreads();  // protect K/V LDS from previous iteration's readers

        // ---- stage K tile: 32 keys x 128 d, bf16, row-major ----
        {
            const int krow = min(kb + kr, T - 1);
            const float* src = kg + (size_t)krow * KSTRIDE + kvh * HD + dq * 16;
            f32x4 f0 = ((const f32x4*)src)[0];
            f32x4 f1 = ((const f32x4*)src)[1];
            f32x4 f2 = ((const f32x4*)src)[2];
            f32x4 f3 = ((const f32x4*)src)[3];
            U8 a, b;
#pragma unroll
            for (int j = 0; j < 4; ++j) {
                a.u[j] = f2b(f0[j]); a.u[4 + j] = f2b(f1[j]);
                b.u[j] = f2b(f2[j]); b.u[4 + j] = f2b(f3[j]);
            }
            *(u32x4*)&Ks[kr * KS_STRIDE + dq * 16]     = a.q;
            *(u32x4*)&Ks[kr * KS_STRIDE + dq * 16 + 8] = b.q;
        }
        // ---- stage V tile transposed: Vt[d][key], packed pair writes ----
        {
            const int r0 = min(kb + 2 * krp,     T - 1);
            const int r1 = min(kb + 2 * krp + 1, T - 1);
            const float* s0 = vg + (size_t)r0 * KSTRIDE + kvh * HD + dq8 * 8;
            const float* s1 = vg + (size_t)r1 * KSTRIDE + kvh * HD + dq8 * 8;
            f32x4 a0 = ((const f32x4*)s0)[0], a1 = ((const f32x4*)s0)[1];
            f32x4 b0 = ((const f32x4*)s1)[0], b1 = ((const f32x4*)s1)[1];
#pragma unroll
            for (int mm = 0; mm < 8; ++mm) {
                float x = (mm < 4) ? a0[mm] : a1[mm - 4];
                float y = (mm < 4) ? b0[mm] : b1[mm - 4];
                unsigned pk = (unsigned)f2b(x) | ((unsigned)f2b(y) << 16);
                *(unsigned*)&Vt[(dq8 * 8 + mm) * VT_STRIDE + 2 * krp] = pk;
            }
        }
        __syncthreads();

        // ---- QK^T: S[16q x 32key] = Q(16x128) . K^T ----
        f32x4 s0 = (f32x4){0.f, 0.f, 0.f, 0.f};
        f32x4 s1 = (f32x4){0.f, 0.f, 0.f, 0.f};
#pragma unroll
        for (int c = 0; c < 4; ++c) {
            U8 b0, b1;
            b0.q = *(const u32x4*)&Ks[li * KS_STRIDE + c * 32 + quad * 8];
            b1.q = *(const u32x4*)&Ks[(16 + li) * KS_STRIDE + c * 32 + quad * 8];
            s0 = __builtin_amdgcn_mfma_f32_16x16x32_bf16(qf[c], b0.v, s0, 0, 0, 0);
            s1 = __builtin_amdgcn_mfma_f32_16x16x32_bf16(qf[c], b1.v, s1, 0, 0, 0);
        }

        // ---- mask + online softmax (base-2 domain) ----
        float p0v[4], p1v[4], alpha[4];
#pragma unroll
        for (int r = 0; r < 4; ++r) {
            const int key0 = kb + li;
            const int key1 = kb + 16 + li;
            float x0 = (key0 >= rstart[r] && key0 <= rowg[r]) ? s0[r] : -3e38f;
            float x1 = (key1 >= rstart[r] && key1 <= rowg[r]) ? s1[r] : -3e38f;
            float tmax = fmaxf(x0, x1);
            tmax = fmaxf(tmax, __shfl_xor(tmax, 1));
            tmax = fmaxf(tmax, __shfl_xor(tmax, 2));
            tmax = fmaxf(tmax, __shfl_xor(tmax, 4));
            tmax = fmaxf(tmax, __shfl_xor(tmax, 8));
            float mnew = fmaxf(m_i[r], tmax);
            alpha[r] = exp2f(m_i[r] - mnew);
            m_i[r] = mnew;
            float p0 = exp2f(x0 - mnew);
            float p1 = exp2f(x1 - mnew);
            float rs = p0 + p1;
            rs += __shfl_xor(rs, 1);
            rs += __shfl_xor(rs, 2);
            rs += __shfl_xor(rs, 4);
            rs += __shfl_xor(rs, 8);
            l_i[r] = l_i[r] * alpha[r] + rs;
            p0v[r] = p0; p1v[r] = p1;
        }

        // rescale O accumulators
#pragma unroll
        for (int nt = 0; nt < 8; ++nt) {
            f32x4 a = acc[nt];
#pragma unroll
            for (int r = 0; r < 4; ++r) a[r] *= alpha[r];
            acc[nt] = a;
        }

        // ---- P: C-layout -> bf16 -> LDS -> A-layout (per-wave buffer, in-wave ordering) ----
        unsigned short* Pw = &Ps[w * 16 * PS_STRIDE];
#pragma unroll
        for (int r = 0; r < 4; ++r) {
            Pw[(quad * 4 + r) * PS_STRIDE + li]      = f2b(p0v[r]);
            Pw[(quad * 4 + r) * PS_STRIDE + 16 + li] = f2b(p1v[r]);
        }
        U8 pa;
        pa.q = *(const u32x4*)&Pw[li * PS_STRIDE + quad * 8];

        // ---- PV: O(16x128) += P(16x32) . V(32x128) ----
#pragma unroll
        for (int nt = 0; nt < 8; ++nt) {
            U8 vb;
            vb.q = *(const u32x4*)&Vt[(nt * 16 + li) * VT_STRIDE + quad * 8];
            acc[nt] = __builtin_amdgcn_mfma_f32_16x16x32_bf16(pa.v, vb.v, acc[nt], 0, 0, 0);
        }
    }

    // ---- epilogue: normalize and store ----
    float inv[4];
#pragma unroll
    for (int r = 0; r < 4; ++r) inv[r] = (l_i[r] > 0.f) ? (1.0f / l_i[r]) : 0.f;
#pragma unroll
    for (int nt = 0; nt < 8; ++nt) {
        f32x4 a = acc[nt];
#pragma unroll
        for (int r = 0; r < 4; ++r) {
            const int rg = rowg[r];
            if (rg < T) {
                out[(size_t)rg * QSTRIDE + hq * HD + nt * 16 + li] = a[r] * inv[r];
            }
        }
    }
}

extern "C" void kernel_launch(void* const* d_in, const int* in_sizes, int n_in,
                              void* d_out, int out_size, void* d_ws, size_t ws_size,
                              hipStream_t stream) {
    const float* q   = (const float*)d_in[0];
    const float* k   = (const float*)d_in[1];
    const float* v   = (const float*)d_in[2];
    const int*   pos = (const int*)d_in[3];
    float* out = (float*)d_out;
    const int T = in_sizes[0] / QSTRIDE;

    dim3 grid((T + 31) / 32, NUM_KV);
    attn_kernel<<<grid, 256, 0, stream>>>(q, k, v, pos, out, T);
}